// Round 5
// baseline (22.183 us; speedup 1.0000x reference)
//
#include <hip/hip_runtime.h>
#include <hip/hip_bf16.h>
#include <math.h>

#define DD 64  // feature dim

typedef __bf16 bf16x8 __attribute__((ext_vector_type(8)));
typedef float f32x4 __attribute__((ext_vector_type(4)));

__device__ inline bf16x8 cvt8(const float4 a, const float4 b) {
  bf16x8 r;
  r[0] = (__bf16)a.x; r[1] = (__bf16)a.y; r[2] = (__bf16)a.z; r[3] = (__bf16)a.w;
  r[4] = (__bf16)b.x; r[5] = (__bf16)b.y; r[6] = (__bf16)b.z; r[7] = (__bf16)b.w;
  return r;
}

// Sum of squares of the bf16-rounded fragment (so d^2 = nx+ny-2dot >= 0).
__device__ inline float norm8(const bf16x8 v, float s) {
  #pragma unroll
  for (int i = 0; i < 8; ++i) {
    const float t = (float)v[i];
    s = fmaf(t, t, s);
  }
  return s;
}

// Fully fused CDist, no LDS, single phase, 8 waves/SIMD:
//   out[i][j] = sqrt(max(||xb_i||^2 + ||yb_j||^2 - 2 xb_i.yb_j, 0))
// Block = 4 waves (2x2), each wave owns a 16x32 output tile (i x j).
// 8192 waves total = 32/CU; __launch_bounds__(256,8) forces <=64 VGPR.
// Norms are computed AFTER the MFMAs from the retained bf16 fragments
// (lower peak register liveness + overlaps MFMA latency).
__global__ __launch_bounds__(256, 8) void cdist_fused(
    const float* __restrict__ x, const float* __restrict__ y,
    float* __restrict__ out, int N, int M) {
  const int lane = threadIdx.x & 63;
  const int wid  = threadIdx.x >> 6;          // 0..3
  const int wr = wid >> 1, wc = wid & 1;      // 2x2 wave grid
  const int i0 = blockIdx.y * 32 + wr * 16;   // wave's x-row base (16 rows)
  const int j0 = blockIdx.x * 64 + wc * 32;   // wave's y-row base (32 rows)
  const int lrow = lane & 15;
  const int kgrp = lane >> 4;

  // Fragment loads (fp32 global -> bf16 regs). A/B layout: lane l holds 8
  // contiguous k-elems of row (l&15) at k-offset (l>>4)*8 (+32 per k-step).
  const float* px  = &x[(size_t)(i0 + lrow) * DD + kgrp * 8];
  const float* py0 = &y[(size_t)(j0 + lrow) * DD + kgrp * 8];
  const float* py1 = &y[(size_t)(j0 + 16 + lrow) * DD + kgrp * 8];

  const bf16x8 a0 = cvt8(*reinterpret_cast<const float4*>(px),
                         *reinterpret_cast<const float4*>(px + 4));
  const bf16x8 a1 = cvt8(*reinterpret_cast<const float4*>(px + 32),
                         *reinterpret_cast<const float4*>(px + 36));
  const bf16x8 b00 = cvt8(*reinterpret_cast<const float4*>(py0),
                          *reinterpret_cast<const float4*>(py0 + 4));
  const bf16x8 b01 = cvt8(*reinterpret_cast<const float4*>(py0 + 32),
                          *reinterpret_cast<const float4*>(py0 + 36));
  const bf16x8 b10 = cvt8(*reinterpret_cast<const float4*>(py1),
                          *reinterpret_cast<const float4*>(py1 + 4));
  const bf16x8 b11 = cvt8(*reinterpret_cast<const float4*>(py1 + 32),
                          *reinterpret_cast<const float4*>(py1 + 36));

  // Swapped-operand MFMA: D[row -> j][col -> i].
  f32x4 acc0 = {}, acc1 = {};
  acc0 = __builtin_amdgcn_mfma_f32_16x16x32_bf16(b00, a0, acc0, 0, 0, 0);
  acc0 = __builtin_amdgcn_mfma_f32_16x16x32_bf16(b01, a1, acc0, 0, 0, 0);
  acc1 = __builtin_amdgcn_mfma_f32_16x16x32_bf16(b10, a0, acc1, 0, 0, 0);
  acc1 = __builtin_amdgcn_mfma_f32_16x16x32_bf16(b11, a1, acc1, 0, 0, 0);

  // Row norms from the bf16 fragments (overlaps MFMA latency), then
  // butterfly over the kgrp bits so every lane holds its row's full norm.
  float sa  = norm8(a1, norm8(a0, 0.f));
  float sb0 = norm8(b01, norm8(b00, 0.f));
  float sb1 = norm8(b11, norm8(b10, 0.f));
  sa  += __shfl_xor(sa, 16, 64);  sa  += __shfl_xor(sa, 32, 64);
  sb0 += __shfl_xor(sb0, 16, 64); sb0 += __shfl_xor(sb0, 32, 64);
  sb1 += __shfl_xor(sb1, 16, 64); sb1 += __shfl_xor(sb1, 32, 64);

  // Epilogue: element (n, reg r) of a lane:
  //   i = i0 + lrow (x-norm = own sa), j = j0 + n*16 + kgrp*4 + r
  //   (y-norm fetched from lane kgrp*4 + r of sb_n).
  #pragma unroll
  for (int n = 0; n < 2; ++n) {
    const f32x4 acc = n ? acc1 : acc0;
    const float sb  = n ? sb1 : sb0;
    float4 res;
    float nyv, d2;
    nyv = __shfl(sb, kgrp * 4 + 0, 64);
    d2 = fmaf(-2.0f, acc[0], sa + nyv); res.x = __builtin_amdgcn_sqrtf(fmaxf(d2, 0.f));
    nyv = __shfl(sb, kgrp * 4 + 1, 64);
    d2 = fmaf(-2.0f, acc[1], sa + nyv); res.y = __builtin_amdgcn_sqrtf(fmaxf(d2, 0.f));
    nyv = __shfl(sb, kgrp * 4 + 2, 64);
    d2 = fmaf(-2.0f, acc[2], sa + nyv); res.z = __builtin_amdgcn_sqrtf(fmaxf(d2, 0.f));
    nyv = __shfl(sb, kgrp * 4 + 3, 64);
    d2 = fmaf(-2.0f, acc[3], sa + nyv); res.w = __builtin_amdgcn_sqrtf(fmaxf(d2, 0.f));
    *reinterpret_cast<float4*>(
        &out[(size_t)(i0 + lrow) * M + j0 + n * 16 + kgrp * 4]) = res;
  }
}

extern "C" void kernel_launch(void* const* d_in, const int* in_sizes, int n_in,
                              void* d_out, int out_size, void* d_ws, size_t ws_size,
                              hipStream_t stream) {
  const float* x = (const float*)d_in[0];
  const float* y = (const float*)d_in[1];
  float* out = (float*)d_out;
  const int N = in_sizes[0] / DD;  // 2048
  const int M = in_sizes[1] / DD;  // 2048

  cdist_fused<<<dim3(M / 64, N / 32), dim3(256), 0, stream>>>(x, y, out, N, M);
}

// Round 7
// 16.175 us; speedup vs baseline: 1.3715x; 1.3715x over previous
//
#include <hip/hip_runtime.h>
#include <hip/hip_bf16.h>
#include <math.h>

#define DD 64  // feature dim

typedef __bf16 bf16x8 __attribute__((ext_vector_type(8)));
typedef float f32x4 __attribute__((ext_vector_type(4)));

// Convert 8 fp32 -> bf16 fragment, accumulating sum of squares of the
// bf16-ROUNDED values into s (so d^2 = nx+ny-2dot = ||xb-yb||^2 >= 0).
__device__ inline bf16x8 cvt8n(const float4 a, const float4 b, float& s) {
  bf16x8 r;
  float t;
  r[0] = (__bf16)a.x; t = (float)r[0]; s = fmaf(t, t, s);
  r[1] = (__bf16)a.y; t = (float)r[1]; s = fmaf(t, t, s);
  r[2] = (__bf16)a.z; t = (float)r[2]; s = fmaf(t, t, s);
  r[3] = (__bf16)a.w; t = (float)r[3]; s = fmaf(t, t, s);
  r[4] = (__bf16)b.x; t = (float)r[4]; s = fmaf(t, t, s);
  r[5] = (__bf16)b.y; t = (float)r[5]; s = fmaf(t, t, s);
  r[6] = (__bf16)b.z; t = (float)r[6]; s = fmaf(t, t, s);
  r[7] = (__bf16)b.w; t = (float)r[7]; s = fmaf(t, t, s);
  return r;
}

// Fully fused CDist, no LDS, no __syncthreads, single phase:
//   out[i][j] = sqrt(max(||xb_i||^2 + ||yb_j||^2 - 2 xb_i.yb_j, 0))
// Block = 4 independent waves (2x2), each wave owns a 32x32 output tile.
// Swapped-operand MFMA (y as A, x as B) -> C/D row maps to j, col to i:
// each lane's 4 acc regs are 4 consecutive j -> one float4 store per frag.
// Output is write-once -> nontemporal stores (no L2 pollution / RMW).
__global__ __launch_bounds__(256) void cdist_fused(
    const float* __restrict__ x, const float* __restrict__ y,
    float* __restrict__ out, int N, int M) {
  const int lane = threadIdx.x & 63;
  const int wid  = threadIdx.x >> 6;         // 0..3
  const int wr = wid >> 1, wc = wid & 1;     // 2x2 wave grid
  const int i0 = blockIdx.y * 64 + wr * 32;  // wave's x-row base
  const int j0 = blockIdx.x * 64 + wc * 32;  // wave's y-row base
  const int lrow = lane & 15;
  const int kgrp = lane >> 4;

  // Fragment loads (fp32 global -> bf16 regs) + partial norms.
  // A/B layout: lane l holds 8 contiguous k-elems of row (l&15) at k-offset
  // (l>>4)*8 (+32 per k-step). Verified rounds 2-5.
  bf16x8 a[2][2], b[2][2];
  float sa[2] = {0.f, 0.f}, sb[2] = {0.f, 0.f};
  #pragma unroll
  for (int m = 0; m < 2; ++m) {
    #pragma unroll
    for (int ks = 0; ks < 2; ++ks) {
      const float* px = &x[(size_t)(i0 + m * 16 + lrow) * DD + ks * 32 + kgrp * 8];
      a[m][ks] = cvt8n(*reinterpret_cast<const float4*>(px),
                       *reinterpret_cast<const float4*>(px + 4), sa[m]);
      const float* py = &y[(size_t)(j0 + m * 16 + lrow) * DD + ks * 32 + kgrp * 8];
      b[m][ks] = cvt8n(*reinterpret_cast<const float4*>(py),
                       *reinterpret_cast<const float4*>(py + 4), sb[m]);
    }
  }

  // Butterfly over the kgrp bits: every lane gets the full norm of the row
  // (base + frag*16 + lrow) it loaded.
  #pragma unroll
  for (int m = 0; m < 2; ++m) {
    sa[m] += __shfl_xor(sa[m], 16, 64);
    sa[m] += __shfl_xor(sa[m], 32, 64);
    sb[m] += __shfl_xor(sb[m], 16, 64);
    sb[m] += __shfl_xor(sb[m], 32, 64);
  }

  // Swapped-operand MFMA: D[row -> j][col -> i].
  f32x4 acc[2][2] = {};  // acc[n][m]
  #pragma unroll
  for (int ks = 0; ks < 2; ++ks)
    #pragma unroll
    for (int n = 0; n < 2; ++n)
      #pragma unroll
      for (int m = 0; m < 2; ++m)
        acc[n][m] = __builtin_amdgcn_mfma_f32_16x16x32_bf16(
            b[n][ks], a[m][ks], acc[n][m], 0, 0, 0);

  // Epilogue: element (m, n, reg r) of a lane:
  //   i = i0 + m*16 + lrow (x-norm = own sa[m])
  //   j = j0 + n*16 + kgrp*4 + r (y-norm from lane kgrp*4+r of sb[n])
  #pragma unroll
  for (int n = 0; n < 2; ++n) {
    float nyv[4];
    #pragma unroll
    for (int r = 0; r < 4; ++r) nyv[r] = __shfl(sb[n], kgrp * 4 + r, 64);
    #pragma unroll
    for (int m = 0; m < 2; ++m) {
      f32x4 res;
      float d2;
      d2 = fmaf(-2.0f, acc[n][m][0], sa[m] + nyv[0]); res[0] = sqrtf(fmaxf(d2, 0.f));
      d2 = fmaf(-2.0f, acc[n][m][1], sa[m] + nyv[1]); res[1] = sqrtf(fmaxf(d2, 0.f));
      d2 = fmaf(-2.0f, acc[n][m][2], sa[m] + nyv[2]); res[2] = sqrtf(fmaxf(d2, 0.f));
      d2 = fmaf(-2.0f, acc[n][m][3], sa[m] + nyv[3]); res[3] = sqrtf(fmaxf(d2, 0.f));
      __builtin_nontemporal_store(
          res, reinterpret_cast<f32x4*>(
              &out[(size_t)(i0 + m * 16 + lrow) * M + j0 + n * 16 + kgrp * 4]));
    }
  }
}

extern "C" void kernel_launch(void* const* d_in, const int* in_sizes, int n_in,
                              void* d_out, int out_size, void* d_ws, size_t ws_size,
                              hipStream_t stream) {
  const float* x = (const float*)d_in[0];
  const float* y = (const float*)d_in[1];
  float* out = (float*)d_out;
  const int N = in_sizes[0] / DD;  // 2048
  const int M = in_sizes[1] / DD;  // 2048

  cdist_fused<<<dim3(M / 64, N / 64), dim3(256), 0, stream>>>(x, y, out, N, M);
}